// Round 4
// baseline (3728.256 us; speedup 1.0000x reference)
//
#include <hip/hip_runtime.h>
#include <stddef.h>

#define NN 50000
#define NE 1000000
#define SLOT 64
#define RSQRT20 0.22360679774997896f

// ---------------- utility ----------------
__global__ __launch_bounds__(256) void k_zero(int* __restrict__ p, int n) {
  int i = blockIdx.x * 256 + threadIdx.x;
  if (i < n) p[i] = 0;
}

// Build fixed-stride CSR (by dst). cnt doubles as cursor and final count.
__global__ __launch_bounds__(256) void k_fill(
    const int* __restrict__ s0, const int* __restrict__ d0,
    const int* __restrict__ s1, const int* __restrict__ d1,
    const int* __restrict__ s2, const int* __restrict__ d2,
    int* __restrict__ c0, int* __restrict__ c1, int* __restrict__ c2,
    int* __restrict__ r0, int* __restrict__ r1, int* __restrict__ r2) {
  int e = blockIdx.x * 256 + threadIdx.x;
  if (e >= NE) return;
  const int* s; const int* d; int* c; int* r;
  if (blockIdx.y == 0)      { s = s0; d = d0; c = c0; r = r0; }
  else if (blockIdx.y == 1) { s = s1; d = d1; c = c1; r = r1; }
  else                      { s = s2; d = d2; c = c2; r = r2; }
  int dn = d[e];
  int pos = atomicAdd(&c[dn], 1);
  if (pos < SLOT) r[dn * SLOT + pos] = s[e];
}

// ---------------- layer-0 big projection: [50000,2000] @ [2000,160] ----------------
// 160 cols = conv1{q,k,v,skip} | conv2{q,k,v,skip}, 20 each.
__global__ __launch_bounds__(256) void k_bigproj(
    const float* __restrict__ X,
    const float* __restrict__ W1, const float* __restrict__ B1,
    const float* __restrict__ W2, const float* __restrict__ B2,
    float* __restrict__ proj, float* __restrict__ stats) {
  __shared__ float xt[32][66];    // [kk][row], padded stride 66 (bank-safe, 8B-aligned pairs)
  __shared__ float wt[32][160];   // [kk][col]
  int tid = threadIdx.x;
  if (blockIdx.x == 0 && tid < 120) stats[tid] = 0.f;  // zero BN stats for phase 0
  int rowbase = blockIdx.x * 64;
  int cg = tid & 7;        // column group (20 cols each)
  int rp = tid >> 3;       // row pair 0..31
  float4 acc0[5], acc1[5];
  {
    int s = cg >> 2, jm = cg & 3;
    const float* bp = (s ? B2 : B1) + jm * 20;
    #pragma unroll
    for (int f4 = 0; f4 < 5; ++f4) {
      acc0[f4] = make_float4(bp[f4*4], bp[f4*4+1], bp[f4*4+2], bp[f4*4+3]);
      acc1[f4] = acc0[f4];
    }
  }
  for (int kt = 0; kt < 2000; kt += 32) {
    int ksz = min(32, 2000 - kt);
    #pragma unroll
    for (int j = 0; j < 8; ++j) {       // stage X tile (64 rows x 32 k), transposed
      int idx = tid + j * 256;
      int row = idx >> 5, kk = idx & 31;
      int r = rowbase + row;
      float v = 0.f;
      if (r < NN && kk < ksz) v = X[(size_t)r * 2000 + kt + kk];
      xt[kk][row] = v;
    }
    #pragma unroll
    for (int j = 0; j < 20; ++j) {      // stage W tile (32 k x 160 cols)
      int idx = tid + j * 256;
      int kk = idx / 160, c = idx - kk * 160;
      float v = 0.f;
      if (kk < ksz) {
        int s = c >= 80; int cc = c - s * 80; int jm = cc / 20, f = cc - jm * 20;
        const float* Wp = s ? W2 : W1;
        v = Wp[(jm * 2000 + kt + kk) * 20 + f];
      }
      wt[kk][c] = v;
    }
    __syncthreads();
    #pragma unroll 4
    for (int kk = 0; kk < 32; ++kk) {
      float2 x01 = *(const float2*)&xt[kk][rp * 2];
      #pragma unroll
      for (int f4 = 0; f4 < 5; ++f4) {
        float4 w = *(const float4*)&wt[kk][cg * 20 + f4 * 4];
        acc0[f4].x += x01.x * w.x; acc0[f4].y += x01.x * w.y;
        acc0[f4].z += x01.x * w.z; acc0[f4].w += x01.x * w.w;
        acc1[f4].x += x01.y * w.x; acc1[f4].y += x01.y * w.y;
        acc1[f4].z += x01.y * w.z; acc1[f4].w += x01.y * w.w;
      }
    }
    __syncthreads();
  }
  int s = cg >> 2, jm = cg & 3;
  float* ob = proj + (size_t)(s * 4 + jm) * 1000000;
  int r0 = rowbase + rp * 2, r1 = r0 + 1;
  if (r0 < NN) {
    float* p = ob + (size_t)r0 * 20;
    #pragma unroll
    for (int f4 = 0; f4 < 5; ++f4) *(float4*)&p[f4*4] = acc0[f4];
  }
  if (r1 < NN) {
    float* p = ob + (size_t)r1 * 20;
    #pragma unroll
    for (int f4 = 0; f4 < 5; ++f4) *(float4*)&p[f4*4] = acc1[f4];
  }
}

// ---------------- later projections: (x1,x2) -> up to 3 convs x {q,k,v,skip} ----------------
// mode 0: input = [x1|x2]; mode 1: input = [x2|x1]. slot*1e6 = output base in proj.
#define WSTR 812   // 800 + 12 pad: bank-spread for cm-indexed reads
__global__ __launch_bounds__(256) void k_proj(
    const float* __restrict__ x1, const float* __restrict__ x2,
    const float* __restrict__ W0, const float* __restrict__ B0, int mode0, int slot0,
    const float* __restrict__ W1, const float* __restrict__ B1, int mode1, int slot1,
    const float* __restrict__ W2, const float* __restrict__ B2, int mode2, int slot2,
    int nconv, float* __restrict__ proj, float* __restrict__ stats) {
  __shared__ float wl[12 * WSTR];
  int tid = threadIdx.x;
  if (blockIdx.x == 0 && tid < 120) stats[tid] = 0.f;
  for (int idx = tid; idx < nconv * 3200; idx += 256) {
    int cm = idx / 800, r = idx - cm * 800;
    int t = cm >> 2;
    const float* Wp = (t == 0) ? W0 : (t == 1 ? W1 : W2);
    wl[cm * WSTR + r] = Wp[(cm & 3) * 800 + r];
  }
  __syncthreads();
  int g = tid / 12, cm = tid - g * 12, t = cm >> 2, jm = cm & 3;
  if (g >= 21 || t >= nconv) return;
  int n0 = blockIdx.x * 84 + g * 4;
  if (n0 >= NN) return;
  const float* Bp = (t == 0) ? B0 : (t == 1 ? B1 : B2);
  int mode = (t == 0) ? mode0 : (t == 1 ? mode1 : mode2);
  int slot = (t == 0) ? slot0 : (t == 1 ? slot1 : slot2);
  const float* A  = mode ? x2 : x1;
  const float* Bx = mode ? x1 : x2;
  int nvalid = min(4, NN - n0);
  float4 acc[4][5];
  #pragma unroll
  for (int m = 0; m < 4; ++m)
    #pragma unroll
    for (int f4 = 0; f4 < 5; ++f4)
      acc[m][f4] = make_float4(Bp[jm*20 + f4*4], Bp[jm*20 + f4*4+1],
                               Bp[jm*20 + f4*4+2], Bp[jm*20 + f4*4+3]);
  const float* wbase = &wl[cm * WSTR];
  #pragma unroll 1
  for (int half = 0; half < 2; ++half) {
    const float* src = half ? Bx : A;
    for (int i = 0; i < 20; ++i) {
      float xv[4];
      #pragma unroll
      for (int m = 0; m < 4; ++m)
        xv[m] = (m < nvalid) ? src[(size_t)(n0 + m) * 20 + i] : 0.f;
      #pragma unroll
      for (int f4 = 0; f4 < 5; ++f4) {
        float4 w = *(const float4*)&wbase[(half * 20 + i) * 20 + f4 * 4];
        #pragma unroll
        for (int m = 0; m < 4; ++m) {
          acc[m][f4].x += xv[m] * w.x; acc[m][f4].y += xv[m] * w.y;
          acc[m][f4].z += xv[m] * w.z; acc[m][f4].w += xv[m] * w.w;
        }
      }
    }
  }
  float* ob = proj + (size_t)(slot + jm) * 1000000;
  #pragma unroll
  for (int m = 0; m < 4; ++m) {
    if (m < nvalid) {
      float* p = ob + (size_t)(n0 + m) * 20;
      #pragma unroll
      for (int f4 = 0; f4 < 5; ++f4) *(float4*)&p[f4*4] = acc[m][f4];
    }
  }
}

// ---------------- edge phase A: w = exp(q[dst].k[src]/sqrt(20)) per CSR slot ----------------
__global__ __launch_bounds__(256) void k_edge_w(
    const int* __restrict__ cnt, const int* __restrict__ csr,
    const float* __restrict__ q, const float* __restrict__ k,
    float* __restrict__ wsl) {
  int gid = blockIdx.x * 256 + threadIdx.x;
  if (gid >= NN * SLOT) return;
  int n = gid >> 6, j = gid & 63;
  int deg = min(cnt[n], SLOT);
  if (j >= deg) return;
  int s = csr[gid];
  const float* qr = q + (size_t)n * 20;
  const float* kr = k + (size_t)s * 20;
  float dot = 0.f;
  #pragma unroll
  for (int f4 = 0; f4 < 5; ++f4) {
    float4 a = *(const float4*)&qr[f4*4];
    float4 b = *(const float4*)&kr[f4*4];
    dot += a.x*b.x + a.y*b.y + a.z*b.z + a.w*b.w;
  }
  wsl[gid] = __expf(dot * RSQRT20);
}

// ---------------- edge phase B: gather-aggregate + skip ----------------
__global__ __launch_bounds__(256) void k_edge_agg(
    const int* __restrict__ cnt, const int* __restrict__ csr,
    const float* __restrict__ wsl, const float* __restrict__ v,
    const float* __restrict__ skip, float* __restrict__ pre) {
  int gid = blockIdx.x * 256 + threadIdx.x;
  if (gid >= NN * 20) return;
  int n = gid / 20, f = gid - n * 20;
  int deg = min(cnt[n], SLOT);
  const int* cs = csr + n * SLOT;
  const float* ws = wsl + n * SLOT;
  float accd = 0.f, acca = 0.f;
  for (int j = 0; j < deg; ++j) {
    float w = ws[j];
    int s = cs[j];
    acca += w * v[(size_t)s * 20 + f];
    accd += w;
  }
  pre[gid] = acca / fmaxf(accd, 1e-16f) + skip[gid];
}

// ---------------- BN stats (sum, sumsq per feature) ----------------
__global__ __launch_bounds__(320) void k_bnstats(
    const float* __restrict__ p0, const float* __restrict__ p1,
    const float* __restrict__ p2, float* __restrict__ stats) {
  const float* p = (blockIdx.y == 0) ? p0 : (blockIdx.y == 1 ? p1 : p2);
  __shared__ float ls[40];
  int tid = threadIdx.x;
  if (tid < 40) ls[tid] = 0.f;
  __syncthreads();
  int f = tid % 20;
  int c = blockIdx.x * 16 + tid / 20;   // 0..1023 (grid.x=64, block=320)
  float s = 0.f, sq = 0.f;
  for (int r = c; r < NN; r += 1024) {
    float v = p[r * 20 + f];
    s += v; sq += v * v;
  }
  atomicAdd(&ls[f], s);
  atomicAdd(&ls[20 + f], sq);
  __syncthreads();
  if (tid < 40) atomicAdd(&stats[blockIdx.y * 40 + tid], ls[tid]);
}

// ---------------- BN apply + leaky relu, write to dst (x1/x2 or fc block) ----------------
__global__ __launch_bounds__(256) void k_bnapply(int nconv,
    const float* __restrict__ pA, const float* __restrict__ gA, const float* __restrict__ bA,
    float* __restrict__ dA, int stA, int ofA,
    const float* __restrict__ pB, const float* __restrict__ gB, const float* __restrict__ bB,
    float* __restrict__ dB, int stB, int ofB,
    const float* __restrict__ pC, const float* __restrict__ gC, const float* __restrict__ bC,
    float* __restrict__ dC, int stC, int ofC,
    const float* __restrict__ stats) {
  int gid = blockIdx.x * 256 + threadIdx.x;
  if (gid >= NN * 20) return;
  int n = gid / 20, f = gid - n * 20;
  for (int c = 0; c < nconv; ++c) {
    const float* p = (c == 0) ? pA : (c == 1 ? pB : pC);
    const float* g = (c == 0) ? gA : (c == 1 ? gB : gC);
    const float* b = (c == 0) ? bA : (c == 1 ? bB : bC);
    float* d = (c == 0) ? dA : (c == 1 ? dB : dC);
    int st = (c == 0) ? stA : (c == 1 ? stB : stC);
    int of = (c == 0) ? ofA : (c == 1 ? ofB : ofC);
    float s1 = stats[c * 40 + f], s2 = stats[c * 40 + 20 + f];
    float mean = s1 * (1.0f / NN);
    float var  = fmaf(-mean, mean, s2 * (1.0f / NN));
    float inv  = rsqrtf(var + 1e-5f);
    float val  = (p[gid] - mean) * inv * g[f] + b[f];
    val = (val >= 0.f) ? val : 0.01f * val;
    d[(size_t)n * st + of + f] = val;
  }
}

// ---------------- final FC: [50000,100] @ [100,2] + b ----------------
__global__ __launch_bounds__(256) void k_fc(
    const float* __restrict__ fc, const float* __restrict__ W,
    const float* __restrict__ b, float* __restrict__ out) {
  int n = blockIdx.x * 256 + threadIdx.x;
  if (n >= NN) return;
  const float* row = fc + (size_t)n * 100;
  float a0 = b[0], a1 = b[1];
  for (int j = 0; j < 100; ++j) {
    float x = row[j];
    a0 += x * W[j * 2];
    a1 += x * W[j * 2 + 1];
  }
  out[n * 2]     = a0;
  out[n * 2 + 1] = a1;
}

// ==================================================================
extern "C" void kernel_launch(void* const* d_in, const int* in_sizes, int n_in,
                              void* d_out, int out_size, void* d_ws, size_t ws_size,
                              hipStream_t stream) {
  (void)in_sizes; (void)n_in; (void)out_size; (void)ws_size;
  const float* features = (const float*)d_in[0];
  const int* edge_index = (const int*)d_in[3];
  const int* same2      = (const int*)d_in[4];
  const int* diff2      = (const int*)d_in[5];
  const float* c1_W0 = (const float*)d_in[6];
  const float* c1_b0 = (const float*)d_in[7];
  const float* c2_W0 = (const float*)d_in[8];
  const float* c2_b0 = (const float*)d_in[9];
  const float* c1_W  = (const float*)d_in[10];
  const float* c1_b  = (const float*)d_in[11];
  const float* c2_W  = (const float*)d_in[12];
  const float* c2_b  = (const float*)d_in[13];
  const float* c3_W  = (const float*)d_in[14];
  const float* c3_b  = (const float*)d_in[15];
  const float* bn1_g = (const float*)d_in[16];
  const float* bn1_b = (const float*)d_in[17];
  const float* bn2_g = (const float*)d_in[18];
  const float* bn2_b = (const float*)d_in[19];
  const float* bn3_g = (const float*)d_in[20];
  const float* bn3_b = (const float*)d_in[21];
  const float* fc_W  = (const float*)d_in[22];
  const float* fc_b  = (const float*)d_in[23];
  float* out = (float*)d_out;

  // ---- workspace layout (all 256B aligned) ----
  char* wsb = (char*)d_ws;
  size_t off = 0;
  auto alloc = [&](size_t bytes) -> void* {
    void* p = wsb + off;
    off += (bytes + 255) & ~(size_t)255;
    return p;
  };
  int*   cntall = (int*)  alloc((size_t)3 * NN * 4);
  int*   csrall = (int*)  alloc((size_t)3 * NN * SLOT * 4);
  float* wslall = (float*)alloc((size_t)3 * NN * SLOT * 4);
  float* proj   = (float*)alloc((size_t)12 * 1000000 * 4);
  float* preA   = (float*)alloc((size_t)1000000 * 4);
  float* preB   = (float*)alloc((size_t)1000000 * 4);
  float* preC   = (float*)alloc((size_t)1000000 * 4);
  float* x1     = (float*)alloc((size_t)1000000 * 4);
  float* x2     = (float*)alloc((size_t)1000000 * 4);
  float* fcbuf  = (float*)alloc((size_t)5000000 * 4);
  float* stats  = (float*)alloc(120 * 4);
  int* cnt0 = cntall;           int* cnt1 = cntall + NN;      int* cnt2 = cntall + 2 * NN;
  int* csr0 = csrall;           int* csr1 = csrall + NN*SLOT; int* csr2 = csrall + 2*NN*SLOT;
  float* wsl0 = wslall;         float* wsl1 = wslall + NN*SLOT; float* wsl2 = wslall + 2*NN*SLOT;

  const dim3 B256(256);
  const int gE   = (NE + 255) / 256;          // 3907
  const int gNF  = (NN * 20 + 255) / 256;     // 3907
  const int gSL  = (NN * SLOT) / 256;         // 12500
  const int gBP  = (NN + 63) / 64;            // 782
  const int gPR  = (NN + 83) / 84;            // 596
  const int gFC  = (NN + 255) / 256;          // 196

  // ---- CSR build (once; reused by all 15 tconvs) ----
  k_zero<<<dim3((3 * NN + 255) / 256), B256, 0, stream>>>(cntall, 3 * NN);
  k_fill<<<dim3(gE, 3), B256, 0, stream>>>(
      same2, same2 + NE, diff2, diff2 + NE, edge_index, edge_index + NE,
      cnt0, cnt1, cnt2, csr0, csr1, csr2);

  // ---- phase 0: big projection + conv1_0 / conv2_0 tconvs ----
  k_bigproj<<<dim3(gBP), B256, 0, stream>>>(features, c1_W0, c1_b0, c2_W0, c2_b0, proj, stats);
  k_edge_w<<<dim3(gSL), B256, 0, stream>>>(cnt0, csr0, proj + 0ull,       proj + 1000000ull, wsl0);
  k_edge_w<<<dim3(gSL), B256, 0, stream>>>(cnt1, csr1, proj + 4000000ull, proj + 5000000ull, wsl1);
  k_edge_agg<<<dim3(gNF), B256, 0, stream>>>(cnt0, csr0, wsl0, proj + 2000000ull, proj + 3000000ull, preA);
  k_edge_agg<<<dim3(gNF), B256, 0, stream>>>(cnt1, csr1, wsl1, proj + 6000000ull, proj + 7000000ull, preB);
  k_bnstats<<<dim3(64, 2), dim3(320), 0, stream>>>(preA, preB, preB, stats);
  k_bnapply<<<dim3(gNF), B256, 0, stream>>>(2,
      preA, bn1_g, bn1_b, x1, 20, 0,
      preB, bn2_g, bn2_b, x2, 20, 0,
      preB, bn2_g, bn2_b, x2, 20, 0, stats);

  // ---- phases i=0..3: 3 convs each ----
  for (int i = 0; i < 4; ++i) {
    k_proj<<<dim3(gPR), B256, 0, stream>>>(x1, x2,
        c1_W + (size_t)i * 3200, c1_b + (size_t)i * 80, 0, 0,
        c2_W + (size_t)i * 3200, c2_b + (size_t)i * 80, 1, 4,
        c3_W + (size_t)i * 3200, c3_b + (size_t)i * 80, 0, 8,
        3, proj, stats);
    k_edge_w<<<dim3(gSL), B256, 0, stream>>>(cnt0, csr0, proj + 0ull,       proj + 1000000ull, wsl0);
    k_edge_w<<<dim3(gSL), B256, 0, stream>>>(cnt1, csr1, proj + 4000000ull, proj + 5000000ull, wsl1);
    k_edge_w<<<dim3(gSL), B256, 0, stream>>>(cnt2, csr2, proj + 8000000ull, proj + 9000000ull, wsl2);
    k_edge_agg<<<dim3(gNF), B256, 0, stream>>>(cnt0, csr0, wsl0, proj + 2000000ull,  proj + 3000000ull,  preA);
    k_edge_agg<<<dim3(gNF), B256, 0, stream>>>(cnt1, csr1, wsl1, proj + 6000000ull,  proj + 7000000ull,  preB);
    k_edge_agg<<<dim3(gNF), B256, 0, stream>>>(cnt2, csr2, wsl2, proj + 10000000ull, proj + 11000000ull, preC);
    k_bnstats<<<dim3(64, 3), dim3(320), 0, stream>>>(preA, preB, preC, stats);
    k_bnapply<<<dim3(gNF), B256, 0, stream>>>(3,
        preA, bn1_g + (i + 1) * 20, bn1_b + (i + 1) * 20, x1, 20, 0,
        preB, bn2_g + (i + 1) * 20, bn2_b + (i + 1) * 20, x2, 20, 0,
        preC, bn3_g + i * 20,       bn3_b + i * 20,       fcbuf, 100, i * 20, stats);
  }

  // ---- final: conv3[4] -> fc block 4 ----
  k_proj<<<dim3(gPR), B256, 0, stream>>>(x1, x2,
      c3_W + 4 * 3200, c3_b + 4 * 80, 0, 8,
      c3_W + 4 * 3200, c3_b + 4 * 80, 0, 0,
      c3_W + 4 * 3200, c3_b + 4 * 80, 0, 0,
      1, proj, stats);
  k_edge_w<<<dim3(gSL), B256, 0, stream>>>(cnt2, csr2, proj + 8000000ull, proj + 9000000ull, wsl2);
  k_edge_agg<<<dim3(gNF), B256, 0, stream>>>(cnt2, csr2, wsl2, proj + 10000000ull, proj + 11000000ull, preC);
  k_bnstats<<<dim3(64, 1), dim3(320), 0, stream>>>(preC, preC, preC, stats);
  k_bnapply<<<dim3(gNF), B256, 0, stream>>>(1,
      preC, bn3_g + 80, bn3_b + 80, fcbuf, 100, 80,
      preC, bn3_g + 80, bn3_b + 80, fcbuf, 100, 80,
      preC, bn3_g + 80, bn3_b + 80, fcbuf, 100, 80, stats);

  // ---- final FC ----
  k_fc<<<dim3(gFC), B256, 0, stream>>>(fcbuf, fc_W, fc_b, out);
}

// Round 6
// 2105.375 us; speedup vs baseline: 1.7708x; 1.7708x over previous
//
#include <hip/hip_runtime.h>
#include <stddef.h>

#define NN 50000
#define NE 1000000
#define SLOT 64
#define RSQRT20 0.22360679774997896f

typedef __attribute__((ext_vector_type(8))) short s16x8;
typedef __attribute__((ext_vector_type(4))) float f32x4;

__device__ __forceinline__ unsigned short f2bf(float x) {
  union { float f; unsigned int u; } cv; cv.f = x;
  unsigned int u = cv.u + 0x7fffu + ((cv.u >> 16) & 1u);  // RNE
  return (unsigned short)(u >> 16);
}
__device__ __forceinline__ float bf2f(unsigned short h) {
  union { unsigned int u; float f; } cv; cv.u = ((unsigned int)h) << 16;
  return cv.f;
}

// ---------------- utility ----------------
__global__ __launch_bounds__(256) void k_zero(int* __restrict__ p, int n) {
  int i = blockIdx.x * 256 + threadIdx.x;
  if (i < n) p[i] = 0;
}

// Build fixed-stride CSR (by dst). cnt doubles as cursor and final count.
__global__ __launch_bounds__(256) void k_fill(
    const int* __restrict__ s0, const int* __restrict__ d0,
    const int* __restrict__ s1, const int* __restrict__ d1,
    const int* __restrict__ s2, const int* __restrict__ d2,
    int* __restrict__ c0, int* __restrict__ c1, int* __restrict__ c2,
    int* __restrict__ r0, int* __restrict__ r1, int* __restrict__ r2) {
  int e = blockIdx.x * 256 + threadIdx.x;
  if (e >= NE) return;
  const int* s; const int* d; int* c; int* r;
  if (blockIdx.y == 0)      { s = s0; d = d0; c = c0; r = r0; }
  else if (blockIdx.y == 1) { s = s1; d = d1; c = c1; r = r1; }
  else                      { s = s2; d = d2; c = c2; r = r2; }
  int dn = d[e];
  int pos = atomicAdd(&c[dn], 1);
  if (pos < SLOT) r[dn * SLOT + pos] = s[e];
}

// ---------------- pack W1|W2 -> Bt_hi/Bt_lo [160][2000] bf16 (split fp32) ----------------
__global__ __launch_bounds__(256) void k_packB(
    const float* __restrict__ W1, const float* __restrict__ W2,
    unsigned short* __restrict__ BtH, unsigned short* __restrict__ BtL) {
  int gid = blockIdx.x * 256 + threadIdx.x;
  if (gid >= 160 * 2000) return;
  int col = gid / 2000, k = gid - col * 2000;
  int s = col >= 80; int cc = col - s * 80; int jm = cc / 20, f = cc - jm * 20;
  const float* Wp = s ? W2 : W1;
  float w = Wp[(jm * 2000 + k) * 20 + f];
  unsigned short h = f2bf(w);
  BtH[(size_t)col * 2000 + k] = h;
  BtL[(size_t)col * 2000 + k] = f2bf(w - bf2f(h));
}

// ---------------- layer-0 projection via split-bf16 MFMA (fp32-accurate) ----------------
// [50000,2000] @ [2000,160]; X = Xh+Xl, W = Wh+Wl; acc += Xh*Wh + Xh*Wl + Xl*Wh.
// 64 rows/block, 4 waves x 16 rows, BK=64, reg-staged prefetch, XOR-swizzled LDS.
__global__ __launch_bounds__(256) void k_mm0(
    const float* __restrict__ X,
    const unsigned short* __restrict__ BtHg, const unsigned short* __restrict__ BtLg,
    const float* __restrict__ B1, const float* __restrict__ B2,
    float* __restrict__ proj, float* __restrict__ stats) {
  __shared__ __attribute__((aligned(16))) char AsH[64 * 128];    // 8 KB
  __shared__ __attribute__((aligned(16))) char AsL[64 * 128];    // 8 KB
  __shared__ __attribute__((aligned(16))) char BsH[160 * 128];   // 20 KB
  __shared__ __attribute__((aligned(16))) char BsL[160 * 128];   // 20 KB
  int tid = threadIdx.x;
  if (blockIdx.x == 0 && tid < 120) stats[tid] = 0.f;  // zero BN stats for phase 0
  int rowbase = blockIdx.x * 64;
  int l = tid & 63, w = tid >> 6;
  int l15 = l & 15, lq = l >> 4;

  f32x4 acc[10];
  #pragma unroll
  for (int n = 0; n < 10; ++n) acc[n] = (f32x4){0.f, 0.f, 0.f, 0.f};

  float4 aReg[4]; float4 bRegH[5]; float4 bRegL[5];
  auto issue = [&](int tt) {
    int kt = tt * 64;
    #pragma unroll
    for (int i = 0; i < 4; ++i) {
      int idx = tid + i * 256;
      int rowL = idx >> 4, q4 = idx & 15;
      int gr = rowbase + rowL;
      int kk = kt + q4 * 4;
      float4 v = make_float4(0.f, 0.f, 0.f, 0.f);
      if (gr < NN && kk + 4 <= 2000)
        v = *(const float4*)(X + (size_t)gr * 2000 + kk);
      aReg[i] = v;
    }
    #pragma unroll
    for (int i = 0; i < 5; ++i) {
      int idx = tid + i * 256;
      int col = idx >> 3, ck = idx & 7;
      int kk = kt + ck * 8;
      float4 vh = make_float4(0.f, 0.f, 0.f, 0.f);
      float4 vl = vh;
      if (kk + 8 <= 2000) {
        vh = *(const float4*)((const float*)(BtHg + (size_t)col * 2000 + kk));
        vl = *(const float4*)((const float*)(BtLg + (size_t)col * 2000 + kk));
      }
      bRegH[i] = vh; bRegL[i] = vl;
    }
  };

  issue(0);
  for (int t = 0; t < 32; ++t) {
    __syncthreads();
    // stage regs -> LDS (compiler inserts vmcnt waits on reg use)
    #pragma unroll
    for (int i = 0; i < 4; ++i) {
      int idx = tid + i * 256;
      int rowL = idx >> 4, q4 = idx & 15;
      ushort4 hh, hl;
      {
        float v0 = aReg[i].x, v1 = aReg[i].y, v2 = aReg[i].z, v3 = aReg[i].w;
        hh.x = f2bf(v0); hl.x = f2bf(v0 - bf2f(hh.x));
        hh.y = f2bf(v1); hl.y = f2bf(v1 - bf2f(hh.y));
        hh.z = f2bf(v2); hl.z = f2bf(v2 - bf2f(hh.z));
        hh.w = f2bf(v3); hl.w = f2bf(v3 - bf2f(hh.w));
      }
      unsigned int byte = (unsigned)rowL * 128u +
          (((unsigned)(q4 * 8)) ^ ((unsigned)((rowL & 7) << 4)));
      *(ushort4*)(AsH + byte) = hh;
      *(ushort4*)(AsL + byte) = hl;
    }
    #pragma unroll
    for (int i = 0; i < 5; ++i) {
      int idx = tid + i * 256;
      int col = idx >> 3, ck = idx & 7;
      unsigned int byte = (unsigned)col * 128u +
          (((unsigned)(ck * 16)) ^ ((unsigned)((col & 7) << 4)));
      *(float4*)(BsH + byte) = bRegH[i];
      *(float4*)(BsL + byte) = bRegL[i];
    }
    __syncthreads();
    if (t < 31) issue(t + 1);   // prefetch overlaps compute below
    #pragma unroll
    for (int ks = 0; ks < 2; ++ks) {
      unsigned int rowL = (unsigned)(w * 16 + l15);
      unsigned int ab = rowL * 128u +
          (((unsigned)(ks * 64 + 16 * lq)) ^ ((rowL & 7u) << 4));
      s16x8 afh = *(const s16x8*)(AsH + ab);
      s16x8 afl = *(const s16x8*)(AsL + ab);
      #pragma unroll
      for (int n = 0; n < 10; ++n) {
        unsigned int colL = (unsigned)(n * 16 + l15);
        unsigned int bb = colL * 128u +
            (((unsigned)(ks * 64 + 16 * lq)) ^ ((colL & 7u) << 4));
        s16x8 bfh = *(const s16x8*)(BsH + bb);
        s16x8 bfl = *(const s16x8*)(BsL + bb);
        acc[n] = __builtin_amdgcn_mfma_f32_16x16x32_bf16(afh, bfh, acc[n], 0, 0, 0);
        acc[n] = __builtin_amdgcn_mfma_f32_16x16x32_bf16(afh, bfl, acc[n], 0, 0, 0);
        acc[n] = __builtin_amdgcn_mfma_f32_16x16x32_bf16(afl, bfh, acc[n], 0, 0, 0);
      }
    }
  }

  // epilogue: D[row=4*lq+r][col=l15] per m89-verified C/D mapping
  #pragma unroll
  for (int n = 0; n < 10; ++n) {
    int col = n * 16 + l15;
    int sb = col / 20, f = col - sb * 20;
    float bias = (col < 80) ? B1[col] : B2[col - 80];
    float* ob = proj + (size_t)sb * 1000000;
    #pragma unroll
    for (int r = 0; r < 4; ++r) {
      int row = rowbase + w * 16 + 4 * lq + r;
      if (row < NN) ob[(size_t)row * 20 + f] = acc[n][r] + bias;
    }
  }
}

// ---------------- later projections: (x1,x2) -> up to 3 convs x {q,k,v,skip} ----------------
// mode 0: input = [x1|x2]; mode 1: input = [x2|x1]. slot*1e6 = output base in proj.
#define WSTR 812   // 800 + 12 pad: bank-spread for cm-indexed reads
__global__ __launch_bounds__(256) void k_proj(
    const float* __restrict__ x1, const float* __restrict__ x2,
    const float* __restrict__ W0, const float* __restrict__ B0, int mode0, int slot0,
    const float* __restrict__ W1, const float* __restrict__ B1, int mode1, int slot1,
    const float* __restrict__ W2, const float* __restrict__ B2, int mode2, int slot2,
    int nconv, float* __restrict__ proj, float* __restrict__ stats) {
  __shared__ float wl[12 * WSTR];
  int tid = threadIdx.x;
  if (blockIdx.x == 0 && tid < 120) stats[tid] = 0.f;
  for (int idx = tid; idx < nconv * 3200; idx += 256) {
    int cm = idx / 800, r = idx - cm * 800;
    int t = cm >> 2;
    const float* Wp = (t == 0) ? W0 : (t == 1 ? W1 : W2);
    wl[cm * WSTR + r] = Wp[(cm & 3) * 800 + r];
  }
  __syncthreads();
  int g = tid / 12, cm = tid - g * 12, t = cm >> 2, jm = cm & 3;
  if (g >= 21 || t >= nconv) return;
  int n0 = blockIdx.x * 84 + g * 4;
  if (n0 >= NN) return;
  const float* Bp = (t == 0) ? B0 : (t == 1 ? B1 : B2);
  int mode = (t == 0) ? mode0 : (t == 1 ? mode1 : mode2);
  int slot = (t == 0) ? slot0 : (t == 1 ? slot1 : slot2);
  const float* A  = mode ? x2 : x1;
  const float* Bx = mode ? x1 : x2;
  int nvalid = min(4, NN - n0);
  float4 acc[4][5];
  #pragma unroll
  for (int m = 0; m < 4; ++m)
    #pragma unroll
    for (int f4 = 0; f4 < 5; ++f4)
      acc[m][f4] = make_float4(Bp[jm*20 + f4*4], Bp[jm*20 + f4*4+1],
                               Bp[jm*20 + f4*4+2], Bp[jm*20 + f4*4+3]);
  const float* wbase = &wl[cm * WSTR];
  #pragma unroll 1
  for (int half = 0; half < 2; ++half) {
    const float* src = half ? Bx : A;
    for (int i = 0; i < 20; ++i) {
      float xv[4];
      #pragma unroll
      for (int m = 0; m < 4; ++m)
        xv[m] = (m < nvalid) ? src[(size_t)(n0 + m) * 20 + i] : 0.f;
      #pragma unroll
      for (int f4 = 0; f4 < 5; ++f4) {
        float4 w = *(const float4*)&wbase[(half * 20 + i) * 20 + f4 * 4];
        #pragma unroll
        for (int m = 0; m < 4; ++m) {
          acc[m][f4].x += xv[m] * w.x; acc[m][f4].y += xv[m] * w.y;
          acc[m][f4].z += xv[m] * w.z; acc[m][f4].w += xv[m] * w.w;
        }
      }
    }
  }
  float* ob = proj + (size_t)(slot + jm) * 1000000;
  #pragma unroll
  for (int m = 0; m < 4; ++m) {
    if (m < nvalid) {
      float* p = ob + (size_t)(n0 + m) * 20;
      #pragma unroll
      for (int f4 = 0; f4 < 5; ++f4) *(float4*)&p[f4*4] = acc[m][f4];
    }
  }
}

// ---------------- edge phase A: w = exp(q[dst].k[src]/sqrt(20)) per CSR slot ----------------
__global__ __launch_bounds__(256) void k_edge_w(
    const int* __restrict__ cnt, const int* __restrict__ csr,
    const float* __restrict__ q, const float* __restrict__ k,
    float* __restrict__ wsl) {
  int gid = blockIdx.x * 256 + threadIdx.x;
  if (gid >= NN * SLOT) return;
  int n = gid >> 6, j = gid & 63;
  int deg = min(cnt[n], SLOT);
  if (j >= deg) return;
  int s = csr[gid];
  const float* qr = q + (size_t)n * 20;
  const float* kr = k + (size_t)s * 20;
  float dot = 0.f;
  #pragma unroll
  for (int f4 = 0; f4 < 5; ++f4) {
    float4 a = *(const float4*)&qr[f4*4];
    float4 b = *(const float4*)&kr[f4*4];
    dot += a.x*b.x + a.y*b.y + a.z*b.z + a.w*b.w;
  }
  wsl[gid] = __expf(dot * RSQRT20);
}

// ---------------- edge phase B: gather-aggregate + skip ----------------
__global__ __launch_bounds__(256) void k_edge_agg(
    const int* __restrict__ cnt, const int* __restrict__ csr,
    const float* __restrict__ wsl, const float* __restrict__ v,
    const float* __restrict__ skip, float* __restrict__ pre) {
  int gid = blockIdx.x * 256 + threadIdx.x;
  if (gid >= NN * 20) return;
  int n = gid / 20, f = gid - n * 20;
  int deg = min(cnt[n], SLOT);
  const int* cs = csr + n * SLOT;
  const float* ws = wsl + n * SLOT;
  float accd = 0.f, acca = 0.f;
  for (int j = 0; j < deg; ++j) {
    float w = ws[j];
    int s = cs[j];
    acca += w * v[(size_t)s * 20 + f];
    accd += w;
  }
  pre[gid] = acca / fmaxf(accd, 1e-16f) + skip[gid];
}

// ---------------- BN stats (sum, sumsq per feature) ----------------
__global__ __launch_bounds__(320) void k_bnstats(
    const float* __restrict__ p0, const float* __restrict__ p1,
    const float* __restrict__ p2, float* __restrict__ stats) {
  const float* p = (blockIdx.y == 0) ? p0 : (blockIdx.y == 1 ? p1 : p2);
  __shared__ float ls[40];
  int tid = threadIdx.x;
  if (tid < 40) ls[tid] = 0.f;
  __syncthreads();
  int f = tid % 20;
  int c = blockIdx.x * 16 + tid / 20;   // 0..1023 (grid.x=64, block=320)
  float s = 0.f, sq = 0.f;
  for (int r = c; r < NN; r += 1024) {
    float v = p[r * 20 + f];
    s += v; sq += v * v;
  }
  atomicAdd(&ls[f], s);
  atomicAdd(&ls[20 + f], sq);
  __syncthreads();
  if (tid < 40) atomicAdd(&stats[blockIdx.y * 40 + tid], ls[tid]);
}

// ---------------- BN apply + leaky relu, write to dst (x1/x2 or fc block) ----------------
__global__ __launch_bounds__(256) void k_bnapply(int nconv,
    const float* __restrict__ pA, const float* __restrict__ gA, const float* __restrict__ bA,
    float* __restrict__ dA, int stA, int ofA,
    const float* __restrict__ pB, const float* __restrict__ gB, const float* __restrict__ bB,
    float* __restrict__ dB, int stB, int ofB,
    const float* __restrict__ pC, const float* __restrict__ gC, const float* __restrict__ bC,
    float* __restrict__ dC, int stC, int ofC,
    const float* __restrict__ stats) {
  int gid = blockIdx.x * 256 + threadIdx.x;
  if (gid >= NN * 20) return;
  int n = gid / 20, f = gid - n * 20;
  for (int c = 0; c < nconv; ++c) {
    const float* p = (c == 0) ? pA : (c == 1 ? pB : pC);
    const float* g = (c == 0) ? gA : (c == 1 ? gB : gC);
    const float* b = (c == 0) ? bA : (c == 1 ? bB : bC);
    float* d = (c == 0) ? dA : (c == 1 ? dB : dC);
    int st = (c == 0) ? stA : (c == 1 ? stB : stC);
    int of = (c == 0) ? ofA : (c == 1 ? ofB : ofC);
    float s1 = stats[c * 40 + f], s2 = stats[c * 40 + 20 + f];
    float mean = s1 * (1.0f / NN);
    float var  = fmaf(-mean, mean, s2 * (1.0f / NN));
    float inv  = rsqrtf(var + 1e-5f);
    float val  = (p[gid] - mean) * inv * g[f] + b[f];
    val = (val >= 0.f) ? val : 0.01f * val;
    d[(size_t)n * st + of + f] = val;
  }
}

// ---------------- final FC: [50000,100] @ [100,2] + b ----------------
__global__ __launch_bounds__(256) void k_fc(
    const float* __restrict__ fc, const float* __restrict__ W,
    const float* __restrict__ b, float* __restrict__ out) {
  int n = blockIdx.x * 256 + threadIdx.x;
  if (n >= NN) return;
  const float* row = fc + (size_t)n * 100;
  float a0 = b[0], a1 = b[1];
  for (int j = 0; j < 100; ++j) {
    float x = row[j];
    a0 += x * W[j * 2];
    a1 += x * W[j * 2 + 1];
  }
  out[n * 2]     = a0;
  out[n * 2 + 1] = a1;
}

// ==================================================================
extern "C" void kernel_launch(void* const* d_in, const int* in_sizes, int n_in,
                              void* d_out, int out_size, void* d_ws, size_t ws_size,
                              hipStream_t stream) {
  (void)in_sizes; (void)n_in; (void)out_size; (void)ws_size;
  const float* features = (const float*)d_in[0];
  const int* edge_index = (const int*)d_in[3];
  const int* same2      = (const int*)d_in[4];
  const int* diff2      = (const int*)d_in[5];
  const float* c1_W0 = (const float*)d_in[6];
  const float* c1_b0 = (const float*)d_in[7];
  const float* c2_W0 = (const float*)d_in[8];
  const float* c2_b0 = (const float*)d_in[9];
  const float* c1_W  = (const float*)d_in[10];
  const float* c1_b  = (const float*)d_in[11];
  const float* c2_W  = (const float*)d_in[12];
  const float* c2_b  = (const float*)d_in[13];
  const float* c3_W  = (const float*)d_in[14];
  const float* c3_b  = (const float*)d_in[15];
  const float* bn1_g = (const float*)d_in[16];
  const float* bn1_b = (const float*)d_in[17];
  const float* bn2_g = (const float*)d_in[18];
  const float* bn2_b = (const float*)d_in[19];
  const float* bn3_g = (const float*)d_in[20];
  const float* bn3_b = (const float*)d_in[21];
  const float* fc_W  = (const float*)d_in[22];
  const float* fc_b  = (const float*)d_in[23];
  float* out = (float*)d_out;

  // ---- workspace layout (all 256B aligned) ----
  char* wsb = (char*)d_ws;
  size_t off = 0;
  auto alloc = [&](size_t bytes) -> void* {
    void* p = wsb + off;
    off += (bytes + 255) & ~(size_t)255;
    return p;
  };
  int*   cntall = (int*)  alloc((size_t)3 * NN * 4);
  int*   csrall = (int*)  alloc((size_t)3 * NN * SLOT * 4);
  float* wslall = (float*)alloc((size_t)3 * NN * SLOT * 4);
  float* proj   = (float*)alloc((size_t)12 * 1000000 * 4);
  float* preA   = (float*)alloc((size_t)1000000 * 4);
  float* preB   = (float*)alloc((size_t)1000000 * 4);
  float* preC   = (float*)alloc((size_t)1000000 * 4);
  float* x1     = (float*)alloc((size_t)1000000 * 4);
  float* x2     = (float*)alloc((size_t)1000000 * 4);
  float* fcbuf  = (float*)alloc((size_t)5000000 * 4);
  float* stats  = (float*)alloc(120 * 4);
  int* cnt0 = cntall;           int* cnt1 = cntall + NN;      int* cnt2 = cntall + 2 * NN;
  int* csr0 = csrall;           int* csr1 = csrall + NN*SLOT; int* csr2 = csrall + 2*NN*SLOT;
  float* wsl0 = wslall;         float* wsl1 = wslall + NN*SLOT; float* wsl2 = wslall + 2*NN*SLOT;
  // Bt hi/lo (bf16 [160][2000] each = 1.28MB total) live in the proj slot-8
  // region, consumed by k_mm0 BEFORE k_proj first writes slot 8. No extra ws.
  unsigned short* BtH = (unsigned short*)(proj + (size_t)8 * 1000000);
  unsigned short* BtL = BtH + (size_t)160 * 2000;

  const dim3 B256(256);
  const int gE   = (NE + 255) / 256;          // 3907
  const int gNF  = (NN * 20 + 255) / 256;     // 3907
  const int gSL  = (NN * SLOT) / 256;         // 12500
  const int gMM  = (NN + 63) / 64;            // 782
  const int gPR  = (NN + 83) / 84;            // 596
  const int gFC  = (NN + 255) / 256;          // 196

  // ---- CSR build (once; reused by all 15 tconvs) ----
  k_zero<<<dim3((3 * NN + 255) / 256), B256, 0, stream>>>(cntall, 3 * NN);
  k_fill<<<dim3(gE, 3), B256, 0, stream>>>(
      same2, same2 + NE, diff2, diff2 + NE, edge_index, edge_index + NE,
      cnt0, cnt1, cnt2, csr0, csr1, csr2);

  // ---- phase 0: big projection (split-bf16 MFMA) + conv1_0 / conv2_0 tconvs ----
  k_packB<<<dim3((160 * 2000 + 255) / 256), B256, 0, stream>>>(c1_W0, c2_W0, BtH, BtL);
  k_mm0<<<dim3(gMM), B256, 0, stream>>>(features, BtH, BtL, c1_b0, c2_b0, proj, stats);
  k_edge_w<<<dim3(gSL), B256, 0, stream>>>(cnt0, csr0, proj + 0ull,       proj + 1000000ull, wsl0);
  k_edge_w<<<dim3(gSL), B256, 0, stream>>>(cnt1, csr1, proj + 4000000ull, proj + 5000000ull, wsl1);
  k_edge_agg<<<dim3(gNF), B256, 0, stream>>>(cnt0, csr0, wsl0, proj + 2000000ull, proj + 3000000ull, preA);
  k_edge_agg<<<dim3(gNF), B256, 0, stream>>>(cnt1, csr1, wsl1, proj + 6000000ull, proj + 7000000ull, preB);
  k_bnstats<<<dim3(64, 2), dim3(320), 0, stream>>>(preA, preB, preB, stats);
  k_bnapply<<<dim3(gNF), B256, 0, stream>>>(2,
      preA, bn1_g, bn1_b, x1, 20, 0,
      preB, bn2_g, bn2_b, x2, 20, 0,
      preB, bn2_g, bn2_b, x2, 20, 0, stats);

  // ---- phases i=0..3: 3 convs each ----
  for (int i = 0; i < 4; ++i) {
    k_proj<<<dim3(gPR), B256, 0, stream>>>(x1, x2,
        c1_W + (size_t)i * 3200, c1_b + (size_t)i * 80, 0, 0,
        c2_W + (size_t)i * 3200, c2_b + (size_t)i * 80, 1, 4,
        c3_W + (size_t)i * 3200, c3_b + (size_t)i * 80, 0, 8,
        3, proj, stats);
    k_edge_w<<<dim3(gSL), B256, 0, stream>>>(cnt0, csr0, proj + 0ull,       proj + 1000000ull, wsl0);
    k_edge_w<<<dim3(gSL), B256, 0, stream>>>(cnt1, csr1, proj + 4000000ull, proj + 5000000ull, wsl1);
    k_edge_w<<<dim3(gSL), B256, 0, stream>>>(cnt2, csr2, proj + 8000000ull, proj + 9000000ull, wsl2);
    k_edge_agg<<<dim3(gNF), B256, 0, stream>>>(cnt0, csr0, wsl0, proj + 2000000ull,  proj + 3000000ull,  preA);
    k_edge_agg<<<dim3(gNF), B256, 0, stream>>>(cnt1, csr1, wsl1, proj + 6000000ull,  proj + 7000000ull,  preB);
    k_edge_agg<<<dim3(gNF), B256, 0, stream>>>(cnt2, csr2, wsl2, proj + 10000000ull, proj + 11000000ull, preC);
    k_bnstats<<<dim3(64, 3), dim3(320), 0, stream>>>(preA, preB, preC, stats);
    k_bnapply<<<dim3(gNF), B256, 0, stream>>>(3,
        preA, bn1_g + (i + 1) * 20, bn1_b + (i + 1) * 20, x1, 20, 0,
        preB, bn2_g + (i + 1) * 20, bn2_b + (i + 1) * 20, x2, 20, 0,
        preC, bn3_g + i * 20,       bn3_b + i * 20,       fcbuf, 100, i * 20, stats);
  }

  // ---- final: conv3[4] -> fc block 4 ----
  k_proj<<<dim3(gPR), B256, 0, stream>>>(x1, x2,
      c3_W + 4 * 3200, c3_b + 4 * 80, 0, 8,
      c3_W + 4 * 3200, c3_b + 4 * 80, 0, 0,
      c3_W + 4 * 3200, c3_b + 4 * 80, 0, 0,
      1, proj, stats);
  k_edge_w<<<dim3(gSL), B256, 0, stream>>>(cnt2, csr2, proj + 8000000ull, proj + 9000000ull, wsl2);
  k_edge_agg<<<dim3(gNF), B256, 0, stream>>>(cnt2, csr2, wsl2, proj + 10000000ull, proj + 11000000ull, preC);
  k_bnstats<<<dim3(64, 1), dim3(320), 0, stream>>>(preC, preC, preC, stats);
  k_bnapply<<<dim3(gNF), B256, 0, stream>>>(1,
      preC, bn3_g + 80, bn3_b + 80, fcbuf, 100, 80,
      preC, bn3_g + 80, bn3_b + 80, fcbuf, 100, 80,
      preC, bn3_g + 80, bn3_b + 80, fcbuf, 100, 80, stats);

  // ---- final FC ----
  k_fc<<<dim3(gFC), B256, 0, stream>>>(fcbuf, fc_W, fc_b, out);
}

// Round 8
// 1852.986 us; speedup vs baseline: 2.0120x; 1.1362x over previous
//
#include <hip/hip_runtime.h>
#include <stddef.h>

#define NN 50000
#define NE 1000000
#define SLOT 64
#define RSQRT20 0.22360679774997896f

typedef __attribute__((ext_vector_type(8))) short s16x8;
typedef __attribute__((ext_vector_type(4))) float f32x4;

__device__ __forceinline__ unsigned short f2bf(float x) {
  union { float f; unsigned int u; } cv; cv.f = x;
  unsigned int u = cv.u + 0x7fffu + ((cv.u >> 16) & 1u);  // RNE
  return (unsigned short)(u >> 16);
}
__device__ __forceinline__ float bf2f(unsigned short h) {
  union { unsigned int u; float f; } cv; cv.u = ((unsigned int)h) << 16;
  return cv.f;
}

// ---------------- utility ----------------
__global__ __launch_bounds__(256) void k_zero(int* __restrict__ p, int n) {
  int i = blockIdx.x * 256 + threadIdx.x;
  if (i < n) p[i] = 0;
}

// Build fixed-stride CSR (by dst), ushort entries (src < 50000 < 65536).
__global__ __launch_bounds__(256) void k_fill(
    const int* __restrict__ s0, const int* __restrict__ d0,
    const int* __restrict__ s1, const int* __restrict__ d1,
    const int* __restrict__ s2, const int* __restrict__ d2,
    int* __restrict__ c0, int* __restrict__ c1, int* __restrict__ c2,
    unsigned short* __restrict__ r0, unsigned short* __restrict__ r1,
    unsigned short* __restrict__ r2) {
  int e = blockIdx.x * 256 + threadIdx.x;
  if (e >= NE) return;
  const int* s; const int* d; int* c; unsigned short* r;
  if (blockIdx.y == 0)      { s = s0; d = d0; c = c0; r = r0; }
  else if (blockIdx.y == 1) { s = s1; d = d1; c = c1; r = r1; }
  else                      { s = s2; d = d2; c = c2; r = r2; }
  int dn = d[e];
  int pos = atomicAdd(&c[dn], 1);
  if (pos < SLOT) r[dn * SLOT + pos] = (unsigned short)s[e];
}

// ---------------- pack W1|W2 -> Bt_hi/Bt_lo [160][2000] bf16 (split fp32) ----------------
__global__ __launch_bounds__(256) void k_packB(
    const float* __restrict__ W1, const float* __restrict__ W2,
    unsigned short* __restrict__ BtH, unsigned short* __restrict__ BtL) {
  int gid = blockIdx.x * 256 + threadIdx.x;
  if (gid >= 160 * 2000) return;
  int col = gid / 2000, k = gid - col * 2000;
  int s = col >= 80; int cc = col - s * 80; int jm = cc / 20, f = cc - jm * 20;
  const float* Wp = s ? W2 : W1;
  float w = Wp[(jm * 2000 + k) * 20 + f];
  unsigned short h = f2bf(w);
  BtH[(size_t)col * 2000 + k] = h;
  BtL[(size_t)col * 2000 + k] = f2bf(w - bf2f(h));
}

// ---------------- layer-0 projection via split-bf16 MFMA (fp32-accurate) ----------------
__global__ __launch_bounds__(256) void k_mm0(
    const float* __restrict__ X,
    const unsigned short* __restrict__ BtHg, const unsigned short* __restrict__ BtLg,
    const float* __restrict__ B1, const float* __restrict__ B2,
    float* __restrict__ proj, float* __restrict__ stats) {
  __shared__ __attribute__((aligned(16))) char AsH[64 * 128];    // 8 KB
  __shared__ __attribute__((aligned(16))) char AsL[64 * 128];    // 8 KB
  __shared__ __attribute__((aligned(16))) char BsH[160 * 128];   // 20 KB
  __shared__ __attribute__((aligned(16))) char BsL[160 * 128];   // 20 KB
  int tid = threadIdx.x;
  if (blockIdx.x == 0 && tid < 120) stats[tid] = 0.f;  // zero BN stats for phase 0
  int rowbase = blockIdx.x * 64;
  int l = tid & 63, w = tid >> 6;
  int l15 = l & 15, lq = l >> 4;

  f32x4 acc[10];
  #pragma unroll
  for (int n = 0; n < 10; ++n) acc[n] = (f32x4){0.f, 0.f, 0.f, 0.f};

  float4 aReg[4]; float4 bRegH[5]; float4 bRegL[5];
  auto issue = [&](int tt) {
    int kt = tt * 64;
    #pragma unroll
    for (int i = 0; i < 4; ++i) {
      int idx = tid + i * 256;
      int rowL = idx >> 4, q4 = idx & 15;
      int gr = rowbase + rowL;
      int kk = kt + q4 * 4;
      float4 v = make_float4(0.f, 0.f, 0.f, 0.f);
      if (gr < NN && kk + 4 <= 2000)
        v = *(const float4*)(X + (size_t)gr * 2000 + kk);
      aReg[i] = v;
    }
    #pragma unroll
    for (int i = 0; i < 5; ++i) {
      int idx = tid + i * 256;
      int col = idx >> 3, ck = idx & 7;
      int kk = kt + ck * 8;
      float4 vh = make_float4(0.f, 0.f, 0.f, 0.f);
      float4 vl = vh;
      if (kk + 8 <= 2000) {
        vh = *(const float4*)((const float*)(BtHg + (size_t)col * 2000 + kk));
        vl = *(const float4*)((const float*)(BtLg + (size_t)col * 2000 + kk));
      }
      bRegH[i] = vh; bRegL[i] = vl;
    }
  };

  issue(0);
  for (int t = 0; t < 32; ++t) {
    __syncthreads();
    #pragma unroll
    for (int i = 0; i < 4; ++i) {
      int idx = tid + i * 256;
      int rowL = idx >> 4, q4 = idx & 15;
      ushort4 hh, hl;
      {
        float v0 = aReg[i].x, v1 = aReg[i].y, v2 = aReg[i].z, v3 = aReg[i].w;
        hh.x = f2bf(v0); hl.x = f2bf(v0 - bf2f(hh.x));
        hh.y = f2bf(v1); hl.y = f2bf(v1 - bf2f(hh.y));
        hh.z = f2bf(v2); hl.z = f2bf(v2 - bf2f(hh.z));
        hh.w = f2bf(v3); hl.w = f2bf(v3 - bf2f(hh.w));
      }
      unsigned int byte = (unsigned)rowL * 128u +
          (((unsigned)(q4 * 8)) ^ ((unsigned)((rowL & 7) << 4)));
      *(ushort4*)(AsH + byte) = hh;
      *(ushort4*)(AsL + byte) = hl;
    }
    #pragma unroll
    for (int i = 0; i < 5; ++i) {
      int idx = tid + i * 256;
      int col = idx >> 3, ck = idx & 7;
      unsigned int byte = (unsigned)col * 128u +
          (((unsigned)(ck * 16)) ^ ((unsigned)((col & 7) << 4)));
      *(float4*)(BsH + byte) = bRegH[i];
      *(float4*)(BsL + byte) = bRegL[i];
    }
    __syncthreads();
    if (t < 31) issue(t + 1);   // prefetch overlaps compute below
    #pragma unroll
    for (int ks = 0; ks < 2; ++ks) {
      unsigned int rowL = (unsigned)(w * 16 + l15);
      unsigned int ab = rowL * 128u +
          (((unsigned)(ks * 64 + 16 * lq)) ^ ((rowL & 7u) << 4));
      s16x8 afh = *(const s16x8*)(AsH + ab);
      s16x8 afl = *(const s16x8*)(AsL + ab);
      #pragma unroll
      for (int n = 0; n < 10; ++n) {
        unsigned int colL = (unsigned)(n * 16 + l15);
        unsigned int bb = colL * 128u +
            (((unsigned)(ks * 64 + 16 * lq)) ^ ((colL & 7u) << 4));
        s16x8 bfh = *(const s16x8*)(BsH + bb);
        s16x8 bfl = *(const s16x8*)(BsL + bb);
        acc[n] = __builtin_amdgcn_mfma_f32_16x16x32_bf16(afh, bfh, acc[n], 0, 0, 0);
        acc[n] = __builtin_amdgcn_mfma_f32_16x16x32_bf16(afh, bfl, acc[n], 0, 0, 0);
        acc[n] = __builtin_amdgcn_mfma_f32_16x16x32_bf16(afl, bfh, acc[n], 0, 0, 0);
      }
    }
  }

  #pragma unroll
  for (int n = 0; n < 10; ++n) {
    int col = n * 16 + l15;
    int sb = col / 20, f = col - sb * 20;
    float bias = (col < 80) ? B1[col] : B2[col - 80];
    float* ob = proj + (size_t)sb * 1000000;
    #pragma unroll
    for (int r = 0; r < 4; ++r) {
      int row = rowbase + w * 16 + 4 * lq + r;
      if (row < NN) ob[(size_t)row * 20 + f] = acc[n][r] + bias;
    }
  }
}

// ---------------- later projections: (x1,x2) -> up to 3 convs x {q,k,v,skip} ----------------
#define WSTR 812
__global__ __launch_bounds__(256) void k_proj(
    const float* __restrict__ x1, const float* __restrict__ x2,
    const float* __restrict__ W0, const float* __restrict__ B0, int mode0, int slot0,
    const float* __restrict__ W1, const float* __restrict__ B1, int mode1, int slot1,
    const float* __restrict__ W2, const float* __restrict__ B2, int mode2, int slot2,
    int nconv, float* __restrict__ proj, float* __restrict__ stats) {
  __shared__ float wl[12 * WSTR];
  int tid = threadIdx.x;
  if (blockIdx.x == 0 && tid < 120) stats[tid] = 0.f;
  for (int idx = tid; idx < nconv * 3200; idx += 256) {
    int cm = idx / 800, r = idx - cm * 800;
    int t = cm >> 2;
    const float* Wp = (t == 0) ? W0 : (t == 1 ? W1 : W2);
    wl[cm * WSTR + r] = Wp[(cm & 3) * 800 + r];
  }
  __syncthreads();
  int g = tid / 12, cm = tid - g * 12, t = cm >> 2, jm = cm & 3;
  if (g >= 21 || t >= nconv) return;
  int n0 = blockIdx.x * 84 + g * 4;
  if (n0 >= NN) return;
  const float* Bp = (t == 0) ? B0 : (t == 1 ? B1 : B2);
  int mode = (t == 0) ? mode0 : (t == 1 ? mode1 : mode2);
  int slot = (t == 0) ? slot0 : (t == 1 ? slot1 : slot2);
  const float* A  = mode ? x2 : x1;
  const float* Bx = mode ? x1 : x2;
  int nvalid = min(4, NN - n0);
  float4 acc[4][5];
  #pragma unroll
  for (int m = 0; m < 4; ++m)
    #pragma unroll
    for (int f4 = 0; f4 < 5; ++f4)
      acc[m][f4] = make_float4(Bp[jm*20 + f4*4], Bp[jm*20 + f4*4+1],
                               Bp[jm*20 + f4*4+2], Bp[jm*20 + f4*4+3]);
  const float* wbase = &wl[cm * WSTR];
  #pragma unroll 1
  for (int half = 0; half < 2; ++half) {
    const float* src = half ? Bx : A;
    for (int i = 0; i < 20; ++i) {
      float xv[4];
      #pragma unroll
      for (int m = 0; m < 4; ++m)
        xv[m] = (m < nvalid) ? src[(size_t)(n0 + m) * 20 + i] : 0.f;
      #pragma unroll
      for (int f4 = 0; f4 < 5; ++f4) {
        float4 w = *(const float4*)&wbase[(half * 20 + i) * 20 + f4 * 4];
        #pragma unroll
        for (int m = 0; m < 4; ++m) {
          acc[m][f4].x += xv[m] * w.x; acc[m][f4].y += xv[m] * w.y;
          acc[m][f4].z += xv[m] * w.z; acc[m][f4].w += xv[m] * w.w;
        }
      }
    }
  }
  float* ob = proj + (size_t)(slot + jm) * 1000000;
  #pragma unroll
  for (int m = 0; m < 4; ++m) {
    if (m < nvalid) {
      float* p = ob + (size_t)(n0 + m) * 20;
      #pragma unroll
      for (int f4 = 0; f4 < 5; ++f4) *(float4*)&p[f4*4] = acc[m][f4];
    }
  }
}

// ---------------- fused edge phase: w = exp(qk) then aggregate, one wave/node ----------------
__global__ __launch_bounds__(256) void k_edge_fused(
    const int* __restrict__ cnt, const unsigned short* __restrict__ csr,
    const float* __restrict__ q, const float* __restrict__ k,
    const float* __restrict__ v, const float* __restrict__ skip,
    float* __restrict__ pre) {
  __shared__ float lw[4][64];
  __shared__ unsigned short lsrc[4][64];
  int tid = threadIdx.x;
  int wv = tid >> 6, j = tid & 63;
  int n = blockIdx.x * 4 + wv;
  if (n >= NN) return;
  int deg = min(cnt[n], SLOT);
  float w = 0.f; int s = 0;
  if (j < deg) {
    s = csr[n * SLOT + j];
    const float* qr = q + (size_t)n * 20;
    const float* kr = k + (size_t)s * 20;
    float dot = 0.f;
    #pragma unroll
    for (int f4 = 0; f4 < 5; ++f4) {
      float4 a = *(const float4*)&qr[f4*4];
      float4 b = *(const float4*)&kr[f4*4];
      dot += a.x*b.x + a.y*b.y + a.z*b.z + a.w*b.w;
    }
    w = __expf(dot * RSQRT20);
  }
  lw[wv][j] = w;
  lsrc[wv][j] = (unsigned short)s;
  // denom: butterfly over all 64 lanes (w=0 beyond deg)
  float accd = w;
  #pragma unroll
  for (int off = 1; off < 64; off <<= 1) accd += __shfl_xor(accd, off);
  // aggregate: 3 residue groups (mod 3), 20 features each; lanes 60-63 idle
  int f = j % 20, jg = j / 20;
  float acca = 0.f;
  if (j < 60) {
    for (int jj = jg; jj < deg; jj += 3) {
      float wj = lw[wv][jj];
      int sj = lsrc[wv][jj];
      acca += wj * v[(size_t)sj * 20 + f];
    }
  }
  // combine the 3 groups: BOTH reads from the pre-accumulation value
  float g1 = __shfl(acca, f + 20);
  float g2 = __shfl(acca, f + 40);
  if (j < 20) {
    float val = (acca + g1 + g2) / fmaxf(accd, 1e-16f) + skip[(size_t)n * 20 + j];
    pre[(size_t)n * 20 + j] = val;
  }
}

// ---------------- BN stats (sum, sumsq per feature) ----------------
__global__ __launch_bounds__(320) void k_bnstats(
    const float* __restrict__ p0, const float* __restrict__ p1,
    const float* __restrict__ p2, float* __restrict__ stats) {
  const float* p = (blockIdx.y == 0) ? p0 : (blockIdx.y == 1 ? p1 : p2);
  __shared__ float ls[40];
  int tid = threadIdx.x;
  if (tid < 40) ls[tid] = 0.f;
  __syncthreads();
  int f = tid % 20;
  int c = blockIdx.x * 16 + tid / 20;
  float s = 0.f, sq = 0.f;
  for (int r = c; r < NN; r += 1024) {
    float v = p[r * 20 + f];
    s += v; sq += v * v;
  }
  atomicAdd(&ls[f], s);
  atomicAdd(&ls[20 + f], sq);
  __syncthreads();
  if (tid < 40) atomicAdd(&stats[blockIdx.y * 40 + tid], ls[tid]);
}

// ---------------- BN apply + leaky relu ----------------
__global__ __launch_bounds__(256) void k_bnapply(int nconv,
    const float* __restrict__ pA, const float* __restrict__ gA, const float* __restrict__ bA,
    float* __restrict__ dA, int stA, int ofA,
    const float* __restrict__ pB, const float* __restrict__ gB, const float* __restrict__ bB,
    float* __restrict__ dB, int stB, int ofB,
    const float* __restrict__ pC, const float* __restrict__ gC, const float* __restrict__ bC,
    float* __restrict__ dC, int stC, int ofC,
    const float* __restrict__ stats) {
  int gid = blockIdx.x * 256 + threadIdx.x;
  if (gid >= NN * 20) return;
  int n = gid / 20, f = gid - n * 20;
  for (int c = 0; c < nconv; ++c) {
    const float* p = (c == 0) ? pA : (c == 1 ? pB : pC);
    const float* g = (c == 0) ? gA : (c == 1 ? gB : gC);
    const float* b = (c == 0) ? bA : (c == 1 ? bB : bC);
    float* d = (c == 0) ? dA : (c == 1 ? dB : dC);
    int st = (c == 0) ? stA : (c == 1 ? stB : stC);
    int of = (c == 0) ? ofA : (c == 1 ? ofB : ofC);
    float s1 = stats[c * 40 + f], s2 = stats[c * 40 + 20 + f];
    float mean = s1 * (1.0f / NN);
    float var  = fmaf(-mean, mean, s2 * (1.0f / NN));
    float inv  = rsqrtf(var + 1e-5f);
    float val  = (p[gid] - mean) * inv * g[f] + b[f];
    val = (val >= 0.f) ? val : 0.01f * val;
    d[(size_t)n * st + of + f] = val;
  }
}

// ---------------- final FC: [50000,100] @ [100,2] + b ----------------
__global__ __launch_bounds__(256) void k_fc(
    const float* __restrict__ fc, const float* __restrict__ W,
    const float* __restrict__ b, float* __restrict__ out) {
  int n = blockIdx.x * 256 + threadIdx.x;
  if (n >= NN) return;
  const float* row = fc + (size_t)n * 100;
  float a0 = b[0], a1 = b[1];
  for (int j = 0; j < 100; ++j) {
    float x = row[j];
    a0 += x * W[j * 2];
    a1 += x * W[j * 2 + 1];
  }
  out[n * 2]     = a0;
  out[n * 2 + 1] = a1;
}

// ==================================================================
extern "C" void kernel_launch(void* const* d_in, const int* in_sizes, int n_in,
                              void* d_out, int out_size, void* d_ws, size_t ws_size,
                              hipStream_t stream) {
  (void)in_sizes; (void)n_in; (void)out_size; (void)ws_size;
  const float* features = (const float*)d_in[0];
  const int* edge_index = (const int*)d_in[3];
  const int* same2      = (const int*)d_in[4];
  const int* diff2      = (const int*)d_in[5];
  const float* c1_W0 = (const float*)d_in[6];
  const float* c1_b0 = (const float*)d_in[7];
  const float* c2_W0 = (const float*)d_in[8];
  const float* c2_b0 = (const float*)d_in[9];
  const float* c1_W  = (const float*)d_in[10];
  const float* c1_b  = (const float*)d_in[11];
  const float* c2_W  = (const float*)d_in[12];
  const float* c2_b  = (const float*)d_in[13];
  const float* c3_W  = (const float*)d_in[14];
  const float* c3_b  = (const float*)d_in[15];
  const float* bn1_g = (const float*)d_in[16];
  const float* bn1_b = (const float*)d_in[17];
  const float* bn2_g = (const float*)d_in[18];
  const float* bn2_b = (const float*)d_in[19];
  const float* bn3_g = (const float*)d_in[20];
  const float* bn3_b = (const float*)d_in[21];
  const float* fc_W  = (const float*)d_in[22];
  const float* fc_b  = (const float*)d_in[23];
  float* out = (float*)d_out;

  // ---- workspace layout ----
  char* wsb = (char*)d_ws;
  size_t off = 0;
  auto alloc = [&](size_t bytes) -> void* {
    void* p = wsb + off;
    off += (bytes + 255) & ~(size_t)255;
    return p;
  };
  int*            cntall = (int*)           alloc((size_t)3 * NN * 4);
  unsigned short* csrall = (unsigned short*)alloc((size_t)3 * NN * SLOT * 2);
  float* proj   = (float*)alloc((size_t)12 * 1000000 * 4);
  float* preA   = (float*)alloc((size_t)1000000 * 4);
  float* preB   = (float*)alloc((size_t)1000000 * 4);
  float* preC   = (float*)alloc((size_t)1000000 * 4);
  float* x1     = (float*)alloc((size_t)1000000 * 4);
  float* x2     = (float*)alloc((size_t)1000000 * 4);
  float* fcbuf  = (float*)alloc((size_t)5000000 * 4);
  float* stats  = (float*)alloc(120 * 4);
  int* cnt0 = cntall;  int* cnt1 = cntall + NN;  int* cnt2 = cntall + 2 * NN;
  unsigned short* csr0 = csrall;
  unsigned short* csr1 = csrall + (size_t)NN * SLOT;
  unsigned short* csr2 = csrall + (size_t)2 * NN * SLOT;
  unsigned short* BtH = (unsigned short*)(proj + (size_t)8 * 1000000);
  unsigned short* BtL = BtH + (size_t)160 * 2000;

  const dim3 B256(256);
  const int gE   = (NE + 255) / 256;          // 3907
  const int gNF  = (NN * 20 + 255) / 256;     // 3907
  const int gEF  = (NN + 3) / 4;              // 12500 (4 nodes/block)
  const int gMM  = (NN + 63) / 64;            // 782
  const int gPR  = (NN + 83) / 84;            // 596
  const int gFC  = (NN + 255) / 256;          // 196

  // ---- CSR build (once; reused by all 15 tconvs) ----
  k_zero<<<dim3((3 * NN + 255) / 256), B256, 0, stream>>>(cntall, 3 * NN);
  k_fill<<<dim3(gE, 3), B256, 0, stream>>>(
      same2, same2 + NE, diff2, diff2 + NE, edge_index, edge_index + NE,
      cnt0, cnt1, cnt2, csr0, csr1, csr2);

  // ---- phase 0 ----
  k_packB<<<dim3((160 * 2000 + 255) / 256), B256, 0, stream>>>(c1_W0, c2_W0, BtH, BtL);
  k_mm0<<<dim3(gMM), B256, 0, stream>>>(features, BtH, BtL, c1_b0, c2_b0, proj, stats);
  k_edge_fused<<<dim3(gEF), B256, 0, stream>>>(cnt0, csr0,
      proj + 0ull, proj + 1000000ull, proj + 2000000ull, proj + 3000000ull, preA);
  k_edge_fused<<<dim3(gEF), B256, 0, stream>>>(cnt1, csr1,
      proj + 4000000ull, proj + 5000000ull, proj + 6000000ull, proj + 7000000ull, preB);
  k_bnstats<<<dim3(64, 2), dim3(320), 0, stream>>>(preA, preB, preB, stats);
  k_bnapply<<<dim3(gNF), B256, 0, stream>>>(2,
      preA, bn1_g, bn1_b, x1, 20, 0,
      preB, bn2_g, bn2_b, x2, 20, 0,
      preB, bn2_g, bn2_b, x2, 20, 0, stats);

  // ---- phases i=0..3 ----
  for (int i = 0; i < 4; ++i) {
    k_proj<<<dim3(gPR), B256, 0, stream>>>(x1, x2,
        c1_W + (size_t)i * 3200, c1_b + (size_t)i * 80, 0, 0,
        c2_W + (size_t)i * 3200, c2_b + (size_t)i * 80, 1, 4,
        c3_W + (size_t)i * 3200, c3_b + (size_t)i * 80, 0, 8,
        3, proj, stats);
    k_edge_fused<<<dim3(gEF), B256, 0, stream>>>(cnt0, csr0,
        proj + 0ull, proj + 1000000ull, proj + 2000000ull, proj + 3000000ull, preA);
    k_edge_fused<<<dim3(gEF), B256, 0, stream>>>(cnt1, csr1,
        proj + 4000000ull, proj + 5000000ull, proj + 6000000ull, proj + 7000000ull, preB);
    k_edge_fused<<<dim3(gEF), B256, 0, stream>>>(cnt2, csr2,
        proj + 8000000ull, proj + 9000000ull, proj + 10000000ull, proj + 11000000ull, preC);
    k_bnstats<<<dim3(64, 3), dim3(320), 0, stream>>>(preA, preB, preC, stats);
    k_bnapply<<<dim3(gNF), B256, 0, stream>>>(3,
        preA, bn1_g + (i + 1) * 20, bn1_b + (i + 1) * 20, x1, 20, 0,
        preB, bn2_g + (i + 1) * 20, bn2_b + (i + 1) * 20, x2, 20, 0,
        preC, bn3_g + i * 20,       bn3_b + i * 20,       fcbuf, 100, i * 20, stats);
  }

  // ---- final: conv3[4] -> fc block 4 ----
  k_proj<<<dim3(gPR), B256, 0, stream>>>(x1, x2,
      c3_W + 4 * 3200, c3_b + 4 * 80, 0, 8,
      c3_W + 4 * 3200, c3_b + 4 * 80, 0, 0,
      c3_W + 4 * 3200, c3_b + 4 * 80, 0, 0,
      1, proj, stats);
  k_edge_fused<<<dim3(gEF), B256, 0, stream>>>(cnt2, csr2,
      proj + 8000000ull, proj + 9000000ull, proj + 10000000ull, proj + 11000000ull, preC);
  k_bnstats<<<dim3(64, 1), dim3(320), 0, stream>>>(preC, preC, preC, stats);
  k_bnapply<<<dim3(gNF), B256, 0, stream>>>(1,
      preC, bn3_g + 80, bn3_b + 80, fcbuf, 100, 80,
      preC, bn3_g + 80, bn3_b + 80, fcbuf, 100, 80,
      preC, bn3_g + 80, bn3_b + 80, fcbuf, 100, 80, stats);

  // ---- final FC ----
  k_fc<<<dim3(gFC), B256, 0, stream>>>(fcbuf, fc_W, fc_b, out);
}